// Round 5
// baseline (1305.632 us; speedup 1.0000x reference)
//
#include <hip/hip_runtime.h>

// 5-layer GRU, H=20, B=256, T=4096, fp32. PyTorch GRU math.
// One block per batch element; 5 waves = one per layer, pipelined over
// KK=16-timestep chunks. Lane g owns gate g (20-FMA hh matvec); producer
// wave computes the next layer's input projection from the h-broadcast
// SGPRs it already holds; 2 on-chain bpermutes/t.
//
// R4: NO t-indexed local arrays anywhere (R2/R3 evidence: VGPR_Count=56 ->
// xr_a/xn_a/hlast lived in scratch; ~2-3 L1-latency round-trips per timestep
// on the serial chain, invisible in FETCH/WRITE since TCC counts HBM only).
//  - consumer xg: per-t LDS reads, prefetched 1 iteration ahead (xbuf rows
//    padded to KK+1 so the prefetch is unguarded)
//  - layer-0 x: one coalesced load/chunk into lanes 0..15 + per-t dynamic
//    v_readlane broadcast (no LDS); next chunk prefetched a chunk ahead
//  - layer-4 h: masked global store per t (fire-and-forget)
//  - iter shape: update h_t -> broadcast h_t -> write proj(h_t); no guards

#define HH 20
#define GG 60
#define NL 5
#define BB 256
#define TT 4096
#define KK 16
#define NC (TT / KK)

struct Params {
  const float* x;
  const float* wih[NL];
  const float* whh[NL];
  const float* bih[NL];
  const float* bhh[NL];
  const float* wout;
  const float* bout;
  float* out;
};

__device__ __forceinline__ float bcast(float v, int j) {        // j: imm
  return __int_as_float(__builtin_amdgcn_readlane(__float_as_int(v), j));
}
__device__ __forceinline__ float bcast_dyn(float v, int j) {    // j: sgpr
  return __int_as_float(__builtin_amdgcn_readlane(__float_as_int(v), j));
}
__device__ __forceinline__ float shfl_idx(float v, int byteidx) {
  return __int_as_float(__builtin_amdgcn_ds_bpermute(byteidx, __float_as_int(v)));
}
// sigmoid(x) = 1/(1 + 2^(-x*log2e)); saturates cleanly (rcp(inf)=0)
__device__ __forceinline__ float fsig(float x) {
  float e = __builtin_amdgcn_exp2f(x * -1.442695041f);
  return __builtin_amdgcn_rcpf(1.0f + e);
}
// tanh(y) = 2*sigmoid(2y) - 1; saturates to +-1 without clamp
__device__ __forceinline__ float ftanh(float y) {
  float e = __builtin_amdgcn_exp2f(y * -2.885390082f);
  return fmaf(2.0f, __builtin_amdgcn_rcpf(1.0f + e), -1.0f);
}

__global__ __launch_bounds__(NL * 64, 1) void gru5_kernel(Params p) {
  // xg handoff: producer layer l (0..3) writes slot l; consumer l+1 reads.
  // KK+1 rows so the t+1 prefetch never needs a guard (row KK is junk).
  __shared__ float xbuf[2][NL - 1][KK + 1][64];
  __shared__ float yp[NL];

  const int tid = threadIdx.x;
  const int l = tid >> 6;          // wave index == layer
  const int lane = tid & 63;
  const int b = blockIdx.x;
  const int g = lane < GG ? lane : GG - 1;            // gate owned by lane
  const int gn = lane < HH ? lane + 2 * HH : GG - 1;  // n-gate column for unit lane

  // ---- weights into registers ----
  float whh_r[HH];
  {
    const float* W = p.whh[l];
    #pragma unroll
    for (int j = 0; j < HH; ++j) whh_r[j] = W[g * HH + j];
  }
  // hh accumulator init: b_hh only for n-gate rows (r/z b_hh folded into xg)
  const float binit = (g >= 2 * HH) ? p.bhh[l][g] : 0.0f;

  // producer weights: next layer's ih row for gate g (+ folded biases)
  float wnx[HH];
  float bnx = 0.0f;
  if (l < NL - 1) {
    const float* W = p.wih[l + 1];
    #pragma unroll
    for (int j = 0; j < HH; ++j) wnx[j] = W[g * HH + j];
    bnx = p.bih[l + 1][g] + (g < 2 * HH ? p.bhh[l + 1][g] : 0.0f);
  }
  // layer 0: scalar input weights (own gate + the n-gate of unit `lane`)
  float w0own = 0.f, b0own = 0.f, w0n = 0.f, b0n = 0.f;
  if (l == 0) {
    w0own = p.wih[0][g];
    b0own = p.bih[0][g] + (g < 2 * HH ? p.bhh[0][g] : 0.0f);
    w0n = p.wih[0][gn];
    b0n = p.bih[0][gn];               // b_ih only (b_hh_n stays in binit)
  }

  const int idx20 = ((lane + 20) & 63) << 2;   // bpermute byte indices
  const int idx40 = ((lane + 40) & 63) << 2;

  float hreg = 0.0f;               // lanes 0..19 carry h[unit]
  float hs[HH];                    // wave-uniform broadcast of h (SGPRs)
  #pragma unroll
  for (int j = 0; j < HH; ++j) hs[j] = 0.0f;

  const float* xrow = p.x + (size_t)b * TT;
  float* hout = p.out + (size_t)b * TT * HH;

  // one GRU timestep: matvec on hs (=h_{t-1}) + gates -> updates hreg
  auto gru_step = [&](float xr, float xn) {
    float a0 = binit, a1 = 0.f, a2 = 0.f, a3 = 0.f;
    #pragma unroll
    for (int j = 0; j < HH; j += 4) {
      a0 = fmaf(whh_r[j],     hs[j],     a0);
      a1 = fmaf(whh_r[j + 1], hs[j + 1], a1);
      a2 = fmaf(whh_r[j + 2], hs[j + 2], a2);
      a3 = fmaf(whh_r[j + 3], hs[j + 3], a3);
    }
    const float gh = (a0 + a1) + (a2 + a3);   // (W_hh h)[g] (+b_hh_n)
    const float sv = xr + gh;                 // full preact (r/z rows)
    const float szn = shfl_idx(sv, idx20);    // z preact for unit lane
    const float ghn = shfl_idx(gh, idx40);    // n-gate h-proj (+b_hh_n)
    const float r = fsig(sv);
    const float z = fsig(szn);
    const float n = ftanh(fmaf(r, ghn, xn));
    hreg = fmaf(z, hreg - n, n);              // (1-z)*n + z*h
  };
  auto refresh_hs = [&]() {
    #pragma unroll
    for (int j = 0; j < HH; ++j) hs[j] = bcast(hreg, j);
  };
  auto proj_write = [&](float* dstrow) {      // next layer's xg row (producers)
    float c0 = bnx, c1 = 0.f;
    #pragma unroll
    for (int j = 0; j < HH; j += 2) {
      c0 = fmaf(wnx[j],     hs[j],     c0);
      c1 = fmaf(wnx[j + 1], hs[j + 1], c1);
    }
    dstrow[lane] = c0 + c1;
  };

  // prime layer-0 x stage for chunk 0 (lanes 0..15 hold the chunk's x)
  float xstage = 0.0f;
  if (l == 0 && lane < KK) xstage = xrow[lane];

  for (int s = 0; s < NC + NL - 1; ++s) {
    const int c = s - l;           // this wave's chunk (wave-uniform)
    if (c >= 0 && c < NC) {
      const int pr = (s + 1) & 1;  // read buffer
      const int pc = s & 1;        // write buffer
      float* dst = &xbuf[pc][l][0][0];

      if (l == 0) {
        // prefetch next chunk's x (a whole chunk of latency to hide)
        float xnl = 0.0f;
        if (lane < KK && c + 1 < NC) xnl = xrow[(c + 1) * KK + lane];
        float xv = bcast_dyn(xstage, 0);
        float xr_c = fmaf(w0own, xv, b0own);
        float xn_c = fmaf(w0n, xv, b0n);
        for (int t = 0; t < KK; ++t) {
          float xvn = bcast_dyn(xstage, (t + 1) & (KK - 1));  // wrap: junk, dead
          float xr_n = fmaf(w0own, xvn, b0own);
          float xn_n = fmaf(w0n, xvn, b0n);
          gru_step(xr_c, xn_c);
          refresh_hs();
          proj_write(dst + t * 64);
          xr_c = xr_n; xn_c = xn_n;
        }
        xstage = xnl;
      } else if (l < NL - 1) {
        const float* src = &xbuf[pr][l - 1][0][0];
        float xr_c = src[g];
        float xn_c = src[gn];
        for (int t = 0; t < KK; ++t) {
          const float* nsrc = src + (t + 1) * 64;   // row KK exists (junk, dead)
          float xr_n = nsrc[g];
          float xn_n = nsrc[gn];
          gru_step(xr_c, xn_c);
          refresh_hs();
          proj_write(dst + t * 64);
          xr_c = xr_n; xn_c = xn_n;
        }
      } else {
        const float* src = &xbuf[pr][l - 1][0][0];
        float xr_c = src[g];
        float xn_c = src[gn];
        float* hp = hout + (size_t)c * KK * HH;
        for (int t = 0; t < KK; ++t) {
          const float* nsrc = src + (t + 1) * 64;
          float xr_n = nsrc[g];
          float xn_n = nsrc[gn];
          gru_step(xr_c, xn_c);
          refresh_hs();                       // keeps hs fresh for next iter
          if (lane < HH) hp[t * HH + lane] = hreg;
          xr_c = xr_n; xn_c = xn_n;
        }
      }

      // ---- epilogue at last chunk: h_n + y_hat partial ----
      if (c == NC - 1) {
        if (lane < HH)
          p.out[(size_t)BB * TT * HH + (size_t)b * NL * HH + l * HH + lane] = hreg;
        float pp = (lane < HH) ? hreg * p.wout[l * HH + lane] : 0.0f;
        #pragma unroll
        for (int off = 32; off > 0; off >>= 1) pp += __shfl_down(pp, off);
        if (lane == 0) yp[l] = pp;
      }
    }
    __syncthreads();
  }

  if (tid == 0) {
    float y = p.bout[0];
    #pragma unroll
    for (int ll = 0; ll < NL; ++ll) y += yp[ll];
    p.out[(size_t)BB * TT * HH + (size_t)BB * NL * HH + b] = y;
  }
}

extern "C" void kernel_launch(void* const* d_in, const int* in_sizes, int n_in,
                              void* d_out, int out_size, void* d_ws, size_t ws_size,
                              hipStream_t stream) {
  Params p;
  p.x = (const float*)d_in[0];
  for (int l = 0; l < NL; ++l) {
    p.wih[l] = (const float*)d_in[1 + 4 * l];
    p.whh[l] = (const float*)d_in[2 + 4 * l];
    p.bih[l] = (const float*)d_in[3 + 4 * l];
    p.bhh[l] = (const float*)d_in[4 + 4 * l];
  }
  p.wout = (const float*)d_in[1 + 4 * NL];
  p.bout = (const float*)d_in[2 + 4 * NL];
  p.out = (float*)d_out;

  gru5_kernel<<<BB, NL * 64, 0, stream>>>(p);
}